// Round 8
// baseline (697.809 us; speedup 1.0000x reference)
//
#include <hip/hip_runtime.h>

typedef unsigned short UST;
typedef __bf16 bf16x8 __attribute__((ext_vector_type(8)));
typedef float floatx4 __attribute__((ext_vector_type(4)));
typedef unsigned short ushort8v __attribute__((ext_vector_type(8)));
typedef unsigned short ushort4v __attribute__((ext_vector_type(4)));

#define N_NODES 20000
#define E_EDGES 320000
#define KE 928         // padded edge-MLP K: [hi 0:256 | hj 256:512 | fd(interleaved sin/cos) 512:896 | le 896:905 | pad:928]
#define M_PAD 20096    // 157*128

static __device__ __forceinline__ UST f2bf(float x){
  unsigned int u = __float_as_uint(x);
  u += 0x7fffu + ((u >> 16) & 1u);   // round-to-nearest-even
  return (UST)(u >> 16);
}
static __device__ __forceinline__ float bf2f(UST u){
  return __uint_as_float(((unsigned int)u) << 16);
}
static __device__ __forceinline__ float siluf(float v){
  return v / (1.0f + __expf(-v));
}

// second-stage GEMM: A from padded LDS tile [128][264], B direct from global [256][Kb]
static __device__ __forceinline__ void mfma_stage2(const UST* At, const UST* Bg,
    int Kb, floatx4 (&acc)[4][4], int lm, int quad, int wM, int wN){
#pragma unroll 2
  for (int k0 = 0; k0 < 256; k0 += 32){
    bf16x8 a[4], b[4];
#pragma unroll
    for (int i = 0; i < 4; ++i)
      a[i] = *(const bf16x8*)(At + (wM + i*16 + lm)*264 + k0 + quad*8);
#pragma unroll
    for (int i = 0; i < 4; ++i)
      b[i] = *(const bf16x8*)(Bg + (size_t)(wN + i*16 + lm)*Kb + k0 + quad*8);
#pragma unroll
    for (int mi = 0; mi < 4; ++mi)
#pragma unroll
      for (int ni = 0; ni < 4; ++ni)
        acc[mi][ni] = __builtin_amdgcn_mfma_f32_16x16x32_bf16(a[mi], b[ni], acc[mi][ni], 0, 0, 0);
  }
}

// ---------------- fused prep: weights + LayerNorm + ltl + edge histogram ----------------
// W1T row map: [0:512)=hi|hj, [512:896)=fd interleaved (col 512+2j+b -> orig 521+b*192+j),
// [896:905)=le (orig 512..520), [905:928)=0
__global__ __launch_bounds__(256) void prep_all(
    const float* __restrict__ We1, const float* __restrict__ We2,
    const float* __restrict__ Wn1, const float* __restrict__ Wn2,
    const float* __restrict__ x, const float* __restrict__ gamma,
    const float* __restrict__ beta, const float* __restrict__ lat,
    const int* __restrict__ esrc, int* __restrict__ cnti,
    UST* __restrict__ W1T, UST* __restrict__ W2T,
    UST* __restrict__ Wn1T, UST* __restrict__ Wn2T,
    UST* __restrict__ h, float* __restrict__ ltl){
  int bid = blockIdx.x, t = threadIdx.x;
  if (bid < 928){                                   // W1T
    int i = bid*256 + t;
    int n = i / KE, k = i % KE;
    float v = 0.0f;
    if (k < 512)      v = We1[(size_t)k*256 + n];
    else if (k < 896){
      int idx = k - 512, j = idx >> 1, b = idx & 1;
      v = We1[(size_t)(521 + b*192 + j)*256 + n];
    }
    else if (k < 905) v = We1[(size_t)(k-384)*256 + n];
    W1T[i] = f2bf(v);
  } else if (bid < 1184){                           // W2T + Wn2T
    int i = (bid-928)*256 + t;
    int n = i >> 8, k = i & 255;
    W2T[i]  = f2bf(We2[(size_t)k*256 + n]);
    Wn2T[i] = f2bf(Wn2[(size_t)k*256 + n]);
  } else if (bid < 1696){                           // Wn1T
    int i = (bid-1184)*256 + t;
    int n = i >> 9, k = i & 511;
    Wn1T[i] = f2bf(Wn1[(size_t)k*256 + n]);
  } else if (bid < 6696){                           // LayerNorm, 4 rows/block
    int wave = t >> 6, lane = t & 63;
    int row = (bid-1696)*4 + wave;
    const float4* xp = (const float4*)(x + (size_t)row * 256);
    float4 v = xp[lane];
    float s  = v.x + v.y + v.z + v.w;
    float sq = v.x*v.x + v.y*v.y + v.z*v.z + v.w*v.w;
#pragma unroll
    for (int o = 32; o > 0; o >>= 1){ s += __shfl_xor(s, o); sq += __shfl_xor(sq, o); }
    float mu  = s * (1.0f/256.0f);
    float var = sq * (1.0f/256.0f) - mu*mu;
    float rs  = rsqrtf(var + 1e-5f);
    float4 g = ((const float4*)gamma)[lane];
    float4 b = ((const float4*)beta)[lane];
    ushort4v o4;
    o4[0] = f2bf((v.x-mu)*rs*g.x + b.x);
    o4[1] = f2bf((v.y-mu)*rs*g.y + b.y);
    o4[2] = f2bf((v.z-mu)*rs*g.z + b.z);
    o4[3] = f2bf((v.w-mu)*rs*g.w + b.w);
    *(ushort4v*)(h + (size_t)row*256 + lane*4) = o4;
  } else if (bid < 6732){                           // ltl = L @ L^T
    int i = (bid-6696)*256 + t;
    if (i < 9000){
      int g = i / 9, ij = i % 9, a = ij / 3, b = ij % 3;
      const float* L = lat + g*9;
      ltl[i] = L[a*3+0]*L[b*3+0] + L[a*3+1]*L[b*3+1] + L[a*3+2]*L[b*3+2];
    }
  } else {                                          // edge src histogram
    int e = (bid-6732)*256 + t;
    if (e < E_EDGES) atomicAdd(&cnti[esrc[e]], 1);
  }
}

// ---------------- CSR build: scan -> fill (+sorted srcs) ----------------
__global__ __launch_bounds__(256) void scan_kernel(const int* __restrict__ cnti,
    int* __restrict__ off, int* __restrict__ head){
  __shared__ int ps[256];
  int t = threadIdx.x;
  const int CH = 80;                       // 256*80 = 20480 >= 20000 (cnti padded)
  const int4* cp = (const int4*)cnti;
  int base = t * CH;
  int s = 0;
#pragma unroll 1
  for (int i = 0; i < CH/4; ++i){
    int4 v = cp[t*(CH/4) + i];
    int idx = base + i*4;
    if (idx   < N_NODES) s += v.x;
    if (idx+1 < N_NODES) s += v.y;
    if (idx+2 < N_NODES) s += v.z;
    if (idx+3 < N_NODES) s += v.w;
  }
  ps[t] = s; __syncthreads();
#pragma unroll 1
  for (int o = 1; o < 256; o <<= 1){
    int v = (t >= o) ? ps[t - o] : 0;
    __syncthreads();
    ps[t] += v;
    __syncthreads();
  }
  int run = (t > 0) ? ps[t-1] : 0;
#pragma unroll 1
  for (int i = 0; i < CH/4; ++i){
    int4 v = cp[t*(CH/4) + i];
    int idx = base + i*4;
    int a4[4] = {v.x, v.y, v.z, v.w};
#pragma unroll
    for (int j = 0; j < 4; ++j){
      int id = idx + j;
      if (id < N_NODES){ off[id] = run; head[id] = run; run += a4[j]; }
    }
  }
  if (t == 255) off[N_NODES] = run;
}

__global__ __launch_bounds__(256) void fill_kernel(const int* __restrict__ src,
    int* __restrict__ head, int* __restrict__ eidx, int* __restrict__ srcs){
  int e = blockIdx.x*256 + threadIdx.x;
  if (e < E_EDGES){
    int s = src[e];
    int p = atomicAdd(&head[s], 1);
    eidx[p] = e;
    srcs[p] = s;
  }
}

// ======== MEGA-KERNEL: edge MLP1 + MLP2 + segmented scatter, barrier-light ========
// Phase 1: NO LDS, NO barriers. A-frags per-lane: hi/hj gathered from h, fd computed
//          (sin/cos in registers), le from ltl. B-frags per-lane from global W1T
//          (L1/L2-resident). acc -> silu -> LDS e1t[128][264].
// Phase 2: A from e1t, B per-lane global W2T; barrier-free K-loop.
// Phase 3: silu -> EsT col-major LDS -> 2-half segmented col sums -> atomicAdd sums.
__global__ __launch_bounds__(512, 4)
void gemm_edge_fused(const UST* __restrict__ h, const int* __restrict__ ei,
                     const int* __restrict__ e2g, const float* __restrict__ fdif,
                     const float* __restrict__ ltl, const UST* __restrict__ W1T,
                     const float* __restrict__ be1, const int* __restrict__ eidx,
                     const UST* __restrict__ W2T, const float* __restrict__ be2,
                     const int* __restrict__ rownode, float* __restrict__ sums){
  __shared__ __attribute__((aligned(16))) UST lds[128*264];  // 67.6KB union
  __shared__ int rn[128];
  UST* e1t = lds;             // ph2: [128 rows][264 cols pad]
  UST* EsT = lds;             // ph3: [256 cols][132 rows pad]
  int t = threadIdx.x;
  int bM = blockIdx.x;
  int lane = t & 63, lm = lane & 15, quad = lane >> 4;
  int wave = t >> 6, wM = (wave >> 2)*64, wN = (wave & 3)*64;
  if (t < 128) rn[t] = rownode[bM*128 + t];

  // per-lane A-row indices (4 rows: wM + i*16 + lm) and B-row offsets
  int eR[4], aoff[4], boff[4];
#pragma unroll
  for (int i = 0; i < 4; ++i){
    eR[i]   = eidx[bM*128 + wM + i*16 + lm];
    aoff[i] = ei[eR[i]] * 256;                 // src rows (hi)
    boff[i] = (wN + i*16 + lm) * KE;
  }
  floatx4 acc[4][4] = {};

  // ---- hi: chunks 0..7 (k 0..255), barrier-free ----
#pragma unroll 2
  for (int c = 0; c < 8; ++c){
    int k = c*32 + quad*8;
    bf16x8 a[4], b[4];
#pragma unroll
    for (int i = 0; i < 4; ++i) a[i] = *(const bf16x8*)(h + aoff[i] + k);
#pragma unroll
    for (int i = 0; i < 4; ++i) b[i] = *(const bf16x8*)(W1T + boff[i] + c*32 + quad*8);
#pragma unroll
    for (int mi = 0; mi < 4; ++mi)
#pragma unroll
      for (int ni = 0; ni < 4; ++ni)
        acc[mi][ni] = __builtin_amdgcn_mfma_f32_16x16x32_bf16(a[mi], b[ni], acc[mi][ni], 0, 0, 0);
  }
  // ---- hj: chunks 8..15 (k 256..511) ----
#pragma unroll
  for (int i = 0; i < 4; ++i) aoff[i] = ei[E_EDGES + eR[i]] * 256;   // dst rows
#pragma unroll 2
  for (int c = 8; c < 16; ++c){
    int k = (c-8)*32 + quad*8;
    bf16x8 a[4], b[4];
#pragma unroll
    for (int i = 0; i < 4; ++i) a[i] = *(const bf16x8*)(h + aoff[i] + k);
#pragma unroll
    for (int i = 0; i < 4; ++i) b[i] = *(const bf16x8*)(W1T + boff[i] + c*32 + quad*8);
#pragma unroll
    for (int mi = 0; mi < 4; ++mi)
#pragma unroll
      for (int ni = 0; ni < 4; ++ni)
        acc[mi][ni] = __builtin_amdgcn_mfma_f32_16x16x32_bf16(a[mi], b[ni], acc[mi][ni], 0, 0, 0);
  }
  // ---- fd: chunks 16..27 (k 512..895), A computed per-lane in registers ----
  float fr[4][3];
#pragma unroll
  for (int i = 0; i < 4; ++i){
    fr[i][0] = fdif[eR[i]*3 + 0];
    fr[i][1] = fdif[eR[i]*3 + 1];
    fr[i][2] = fdif[eR[i]*3 + 2];
  }
#pragma unroll 1
  for (int c = 16; c < 28; ++c){
    int jb = (c-16)*16 + quad*4;          // 4 sin/cos pairs per frag
    ushort8v av[4];
#pragma unroll
    for (int p = 0; p < 4; ++p){
      int jj = jb + p;
      int dim = jj >> 6;
      float kf = (float)(jj & 63);
#pragma unroll
      for (int i = 0; i < 4; ++i){
        float f = (dim == 0) ? fr[i][0] : ((dim == 1) ? fr[i][1] : fr[i][2]);
        float q = __builtin_amdgcn_fractf(f * kf);
        av[i][2*p]   = f2bf(__builtin_amdgcn_sinf(q));
        av[i][2*p+1] = f2bf(__builtin_amdgcn_cosf(q));
      }
    }
    bf16x8 b[4];
#pragma unroll
    for (int i = 0; i < 4; ++i) b[i] = *(const bf16x8*)(W1T + boff[i] + c*32 + quad*8);
#pragma unroll
    for (int mi = 0; mi < 4; ++mi)
#pragma unroll
      for (int ni = 0; ni < 4; ++ni)
        acc[mi][ni] = __builtin_amdgcn_mfma_f32_16x16x32_bf16(
            *(const bf16x8*)&av[mi], b[ni], acc[mi][ni], 0, 0, 0);
  }
  // ---- le: chunk 28 (k 896..927): 9 ltl values + zero pad ----
  {
    ushort8v av[4];
#pragma unroll
    for (int i = 0; i < 4; ++i){
      int gg = e2g[eR[i]] * 9;
#pragma unroll
      for (int j = 0; j < 8; ++j){
        int c9 = quad*8 + j;
        av[i][j] = (c9 < 9) ? f2bf(ltl[gg + c9]) : (UST)0;
      }
    }
    bf16x8 b[4];
#pragma unroll
    for (int i = 0; i < 4; ++i) b[i] = *(const bf16x8*)(W1T + boff[i] + 896 + quad*8);
#pragma unroll
    for (int mi = 0; mi < 4; ++mi)
#pragma unroll
      for (int ni = 0; ni < 4; ++ni)
        acc[mi][ni] = __builtin_amdgcn_mfma_f32_16x16x32_bf16(
            *(const bf16x8*)&av[mi], b[ni], acc[mi][ni], 0, 0, 0);
  }
  // phase-1 epilogue: silu -> bf16 into LDS e1t
#pragma unroll
  for (int mi = 0; mi < 4; ++mi)
#pragma unroll
    for (int r = 0; r < 4; ++r){
      int ml = wM + mi*16 + quad*4 + r;
#pragma unroll
      for (int ni = 0; ni < 4; ++ni){
        int nl = wN + ni*16 + lm;
        float v = acc[mi][ni][r] + be1[nl];
        e1t[ml*264 + nl] = f2bf(siluf(v));
      }
    }
  __syncthreads();

  // ---- phase 2: barrier-free K-loop, A from e1t, B from global W2T ----
  floatx4 acc2[4][4] = {};
  mfma_stage2(e1t, W2T, 256, acc2, lm, quad, wM, wN);
  __syncthreads();   // e1t reads done; union becomes EsT

  // ---- phase 3: silu + transpose-store to EsT, 2-half segmented col sums ----
#pragma unroll
  for (int mi = 0; mi < 4; ++mi)
#pragma unroll
    for (int ni = 0; ni < 4; ++ni){
      int nl = wN + ni*16 + lm;
      int ml = wM + mi*16 + quad*4;
      ushort4v pk;
#pragma unroll
      for (int r = 0; r < 4; ++r)
        pk[r] = f2bf(siluf(acc2[mi][ni][r] + be2[nl]));
      *(ushort4v*)&EsT[nl*132 + ml] = pk;
    }
  __syncthreads();
  {
    int c = t & 255, hh = t >> 8;        // all 512 threads: (col, row-half)
    int rbeg = hh * 64;
    int cur = rn[rbeg];
    float run = 0.0f;
#pragma unroll 1
    for (int r = rbeg; r < rbeg + 64; r += 4){
      ushort4v v4 = *(const ushort4v*)&EsT[c*132 + r];
#pragma unroll
      for (int q2 = 0; q2 < 4; ++q2){
        int nd = rn[r + q2];
        if (nd != cur){ atomicAdd(&sums[(size_t)cur*256 + c], run); run = 0.0f; cur = nd; }
        run += bf2f(v4[q2]);
      }
    }
    atomicAdd(&sums[(size_t)cur*256 + c], run);
  }
}

// ======== fused node MLP1 + MLP2, barrier-light ========
// Phase 1: A per-lane (h rows sequential; agg built from sums/deg), B per-lane global.
// Phase 2: A from y1t LDS, B per-lane global Wn2T; silu + resid -> fp32 out.
__global__ __launch_bounds__(512, 4)
void gemm_node12(const UST* __restrict__ h, const float* __restrict__ sums,
                 const int* __restrict__ offs, const UST* __restrict__ B1,
                 const float* __restrict__ bn1, const UST* __restrict__ B2,
                 const float* __restrict__ bn2,
                 float* __restrict__ out_f, const float* __restrict__ resid){
  __shared__ __attribute__((aligned(16))) UST lds[128*264];
  UST* y1t = lds;
  int t = threadIdx.x;
  int bM = blockIdx.x;
  int lane = t & 63, lm = lane & 15, quad = lane >> 4;
  int wave = t >> 6, wM = (wave >> 2)*64, wN = (wave & 3)*64;
  int rowg[4]; bool val[4]; float inv[4]; int boff[4];
#pragma unroll
  for (int i = 0; i < 4; ++i){
    rowg[i] = bM*128 + wM + i*16 + lm;
    val[i] = rowg[i] < N_NODES;
    int deg = val[i] ? (offs[rowg[i]+1] - offs[rowg[i]]) : 1;
    inv[i] = 1.0f / fmaxf((float)deg, 1.0f);
    boff[i] = (wN + i*16 + lm) * 512;
  }
  const ushort8v z8 = {0,0,0,0,0,0,0,0};
  floatx4 acc[4][4] = {};
  // ---- chunks 0..7: h half ----
#pragma unroll 2
  for (int c = 0; c < 8; ++c){
    int k = c*32 + quad*8;
    bf16x8 a[4], b[4];
#pragma unroll
    for (int i = 0; i < 4; ++i)
      a[i] = val[i] ? *(const bf16x8*)(h + (size_t)rowg[i]*256 + k) : *(const bf16x8*)&z8;
#pragma unroll
    for (int i = 0; i < 4; ++i) b[i] = *(const bf16x8*)(B1 + boff[i] + c*32 + quad*8);
#pragma unroll
    for (int mi = 0; mi < 4; ++mi)
#pragma unroll
      for (int ni = 0; ni < 4; ++ni)
        acc[mi][ni] = __builtin_amdgcn_mfma_f32_16x16x32_bf16(a[mi], b[ni], acc[mi][ni], 0, 0, 0);
  }
  // ---- chunks 8..15: agg half from sums/deg ----
#pragma unroll 1
  for (int c = 8; c < 16; ++c){
    int k = (c-8)*32 + quad*8;
    ushort8v av[4];
#pragma unroll
    for (int i = 0; i < 4; ++i){
      av[i] = z8;
      if (val[i]){
        const float* sp = sums + (size_t)rowg[i]*256 + k;
        float4 s0 = *(const float4*)sp;
        float4 s1 = *(const float4*)(sp + 4);
        av[i][0]=f2bf(s0.x*inv[i]); av[i][1]=f2bf(s0.y*inv[i]);
        av[i][2]=f2bf(s0.z*inv[i]); av[i][3]=f2bf(s0.w*inv[i]);
        av[i][4]=f2bf(s1.x*inv[i]); av[i][5]=f2bf(s1.y*inv[i]);
        av[i][6]=f2bf(s1.z*inv[i]); av[i][7]=f2bf(s1.w*inv[i]);
      }
    }
    bf16x8 b[4];
#pragma unroll
    for (int i = 0; i < 4; ++i) b[i] = *(const bf16x8*)(B1 + boff[i] + c*32 + quad*8);
#pragma unroll
    for (int mi = 0; mi < 4; ++mi)
#pragma unroll
      for (int ni = 0; ni < 4; ++ni)
        acc[mi][ni] = __builtin_amdgcn_mfma_f32_16x16x32_bf16(
            *(const bf16x8*)&av[mi], b[ni], acc[mi][ni], 0, 0, 0);
  }
  // epilogue 1: silu -> y1t
#pragma unroll
  for (int mi = 0; mi < 4; ++mi)
#pragma unroll
    for (int r = 0; r < 4; ++r){
      int ml = wM + mi*16 + quad*4 + r;
#pragma unroll
      for (int ni = 0; ni < 4; ++ni){
        int nl = wN + ni*16 + lm;
        y1t[ml*264 + nl] = f2bf(siluf(acc[mi][ni][r] + bn1[nl]));
      }
    }
  __syncthreads();
  // phase 2: barrier-free
  floatx4 acc2[4][4] = {};
  mfma_stage2(y1t, B2, 256, acc2, lm, quad, wM, wN);
  int mbase = bM*128 + wM + quad*4;
  int nbase = wN + lm;
#pragma unroll
  for (int mi = 0; mi < 4; ++mi)
#pragma unroll
    for (int r = 0; r < 4; ++r){
      int m = mbase + mi*16 + r;
      if (m < N_NODES){
#pragma unroll
        for (int ni = 0; ni < 4; ++ni){
          int n = nbase + ni*16;
          float v = siluf(acc2[mi][ni][r] + bn2[n]);
          out_f[(size_t)m*256 + n] = resid[(size_t)m*256 + n] + v;
        }
      }
    }
}

extern "C" void kernel_launch(void* const* d_in, const int* in_sizes, int n_in,
                              void* d_out, int out_size, void* d_ws, size_t ws_size,
                              hipStream_t stream){
  (void)in_sizes; (void)n_in; (void)out_size; (void)ws_size;
  const float* node_features = (const float*)d_in[0];
  const float* lattices      = (const float*)d_in[1];
  const int*   edge_index    = (const int*)d_in[2];   // [2,E]: row0=src, row1=dst
  const int*   edge2graph    = (const int*)d_in[3];
  const float* frac_diff     = (const float*)d_in[4];
  const float* ln_gamma      = (const float*)d_in[6];
  const float* ln_beta       = (const float*)d_in[7];
  const float* We1 = (const float*)d_in[8];
  const float* be1 = (const float*)d_in[9];
  const float* We2 = (const float*)d_in[10];
  const float* be2 = (const float*)d_in[11];
  const float* Wn1 = (const float*)d_in[12];
  const float* bn1 = (const float*)d_in[13];
  const float* Wn2 = (const float*)d_in[14];
  const float* bn2 = (const float*)d_in[15];

  char* w = (char*)d_ws;
  size_t off_b = 0;
  auto carve = [&](size_t bytes) -> char* {
    char* p = w + off_b; off_b += (bytes + 1023) & ~(size_t)1023; return p;
  };
  UST*   W1T  = (UST*)carve((size_t)256*KE*2);
  UST*   W2T  = (UST*)carve((size_t)256*256*2);
  UST*   Wn1T = (UST*)carve((size_t)256*512*2);
  UST*   Wn2T = (UST*)carve((size_t)256*256*2);
  UST*   hbf  = (UST*)carve((size_t)N_NODES*256*2);
  float* ltl  = (float*)carve((size_t)9000*4);
  int*   cnti = (int*)carve((size_t)20480*4);          // padded for int4 scan
  int*   offs = (int*)carve((size_t)(N_NODES+1)*4);
  int*   head = (int*)carve((size_t)N_NODES*4);
  int*   eidx = (int*)carve((size_t)E_EDGES*4);
  int*   srcs = (int*)carve((size_t)E_EDGES*4);        // sorted src per CSR slot
  float* sums = (float*)carve((size_t)N_NODES*256*4);

  hipMemsetAsync(cnti, 0, (size_t)20480*4, stream);
  hipMemsetAsync(sums, 0, (size_t)N_NODES*256*4, stream);

  prep_all<<<6732 + E_EDGES/256, 256, 0, stream>>>(We1, We2, Wn1, Wn2,
      node_features, ln_gamma, ln_beta, lattices, edge_index, cnti,
      W1T, W2T, Wn1T, Wn2T, hbf, ltl);

  scan_kernel<<<1, 256, 0, stream>>>(cnti, offs, head);
  fill_kernel<<<E_EDGES/256, 256, 0, stream>>>(edge_index, head, eidx, srcs);

  gemm_edge_fused<<<E_EDGES/128, 512, 0, stream>>>(
      hbf, edge_index, edge2graph, frac_diff, ltl, W1T, be1, eidx,
      W2T, be2, srcs, sums);

  gemm_node12<<<M_PAD/128, 512, 0, stream>>>(
      hbf, sums, offs, Wn1T, bn1, Wn2T, bn2, (float*)d_out, node_features);
}